// Round 8
// baseline (744.774 us; speedup 1.0000x reference)
//
#include <hip/hip_runtime.h>
#include <cstdint>
#include <cstddef>

#define JAX_PARTITIONABLE 1

namespace {

constexpr int Bsz = 16, Nn = 1024, Dd = 256, Kk = 16, Ss = 512;
constexpr uint32_t BN = (uint32_t)Bsz * Nn;                    // 16384
constexpr int ZQ_SIZE = Bsz * Nn * Dd;                          // 4194304
constexpr int PQ_OFF = ZQ_SIZE;
constexpr int PROB_OFF = ZQ_SIZE + 1;
constexpr int BNS = Bsz * Nn * Ss;                              // 8388608
constexpr int LP_OFF = PROB_OFF + BNS;

// workspace layout (float offsets)
constexpr int WS_CP = 0;                           // 256
constexpr int WS_B2 = 256;                         // K*S = 8192
constexpr int WS_WB2 = WS_B2 + Kk * Ss;            // B*S = 8192
constexpr int WS_WBF = WS_WB2 + Bsz * Ss;          // wbooks bf16 [b][s][d]: 2M shorts
constexpr int WS_BBF = WS_WBF + Bsz * Ss * Dd;     // books bf16
constexpr int WS_BTF = WS_BBF + (Kk * Ss * Dd) / 2; // bookT bf16 [k][d][s]
// total ~4.2M floats ~ 16.9 MB

constexpr float LOG2E = 1.4426950408889634f;

typedef __attribute__((ext_vector_type(8))) short bf16x8;
typedef __attribute__((ext_vector_type(4))) short short4v;
typedef __attribute__((ext_vector_type(4))) float f32x4;

// hw transcendental wrappers (v_exp_f32 / v_log_f32 are base-2)
__device__ __forceinline__ float hw_exp2(float x) { return __builtin_amdgcn_exp2f(x); }
__device__ __forceinline__ float hw_log2(float x) { return __builtin_amdgcn_logf(x); }

struct KP { uint32_t a, b; };

__host__ __device__ constexpr KP tf2x32(uint32_t k0, uint32_t k1,
                                        uint32_t x0, uint32_t x1) {
  uint32_t ks[3] = {k0, k1, k0 ^ k1 ^ 0x1BD11BDAu};
  const int rot[2][4] = {{13, 15, 26, 6}, {17, 29, 16, 24}};
  x0 += ks[0];
  x1 += ks[1];
#pragma unroll
  for (int i = 0; i < 5; ++i) {
#pragma unroll
    for (int j = 0; j < 4; ++j) {
      int r = rot[i & 1][j];
      x0 += x1;
      x1 = (x1 << r) | (x1 >> (32 - r));
      x1 ^= x0;
    }
    x0 += ks[(i + 1) % 3];
    x1 += ks[(i + 2) % 3] + (uint32_t)(i + 1);
  }
  return {x0, x1};
}

#if JAX_PARTITIONABLE
constexpr KP KG1 = tf2x32(0u, 42u, 0u, 0u);
constexpr KP KG2 = tf2x32(0u, 42u, 0u, 1u);
#else
constexpr KP KH0 = tf2x32(0u, 42u, 0u, 2u);
constexpr KP KH1 = tf2x32(0u, 42u, 1u, 3u);
constexpr KP KG1 = {KH0.a, KH1.a};
constexpr KP KG2 = {KH0.b, KH1.b};
#endif

__device__ __forceinline__ float jax_gumbel(KP key, uint32_t idx, uint32_t half) {
#if JAX_PARTITIONABLE
  (void)half;
  KP h = tf2x32(key.a, key.b, 0u, idx);
  uint32_t bits = h.a ^ h.b;
#else
  uint32_t lo = idx < half ? idx : idx - half;
  KP h = tf2x32(key.a, key.b, lo, lo + half);
  uint32_t bits = idx < half ? h.a : h.b;
#endif
  float u = __uint_as_float((bits >> 9) | 0x3F800000u) - 1.0f;
  return -__logf(-__logf(u + 1e-10f) + 1e-10f);
}

// gumbel scaled into the exp2 softmax domain: returns g * 2 * log2e
// (= -2*log2(y), exact same quantity with one fewer rounding).
__device__ __forceinline__ float jax_gumbel_w2(KP key, uint32_t idx) {
  KP h = tf2x32(key.a, key.b, 0u, idx);
  uint32_t bits = h.a ^ h.b;
  float u = __uint_as_float((bits >> 9) | 0x3F800000u) - 1.0f;
  float y = -__logf(u + 1e-10f) + 1e-10f;
  return -2.0f * hw_log2(y);
}

__device__ __forceinline__ float prec_q(const float* p) {
  return 0.5f / fmaxf(1.0f + expf(p[0]), 1e-10f);
}

__device__ __forceinline__ short f2bf(float x) {  // RNE f32->bf16
  uint32_t u = __float_as_uint(x);
  uint32_t r = (u + 0x7FFFu + ((u >> 16) & 1u)) >> 16;
  return (short)r;
}

// ---------------- K1: c_probs (B,K) + precision_q ----------------
__global__ void __launch_bounds__(256) cprobs_kernel(
    const float* __restrict__ c_logits, const float* __restrict__ lpq,
    const float* __restrict__ lpq_cls, float* __restrict__ ws,
    float* __restrict__ out) {
  __shared__ float sl[256];
  const int t = threadIdx.x;
  const float pqc = prec_q(lpq_cls);
  float g = jax_gumbel(KG1, (uint32_t)t, 128u);
  sl[t] = (c_logits[t] * pqc + g) * 2.0f;  // /TEMP, TEMP=0.5
  __syncthreads();
  const int b = t >> 4;
  float m = -3.0e38f;
  for (int j = 0; j < 16; ++j) m = fmaxf(m, sl[b * 16 + j]);
  float sum = 0.f;
  for (int j = 0; j < 16; ++j) sum += expf(sl[b * 16 + j] - m);
  ws[WS_CP + t] = expf(sl[t] - m) / sum;
  if (t == 0) out[PQ_OFF] = prec_q(lpq);
}

// ---------------- K2: b2 (K*S) ----------------
__global__ void __launch_bounds__(256) norms_kernel(
    const float* __restrict__ books, float* __restrict__ ws) {
  const int row = blockIdx.x * 4 + (threadIdx.x >> 6);
  const int lane = threadIdx.x & 63;
  float4 v = ((const float4*)(books + (size_t)row * Dd))[lane];
  float s = v.x * v.x + v.y * v.y + v.z * v.z + v.w * v.w;
#pragma unroll
  for (int d = 1; d < 64; d <<= 1) s += __shfl_xor(s, d);
  if (lane == 0) ws[WS_B2 + row] = s;
}

// ---------------- K3: books -> bf16 + transposed bf16 ----------------
__global__ void __launch_bounds__(256) prep_kernel(
    const float* __restrict__ books, float* __restrict__ ws) {
  __shared__ short tile[16 * 256];
  const int k = blockIdx.x >> 5;
  const int s0 = (blockIdx.x & 31) << 4;
  short* bbf = (short*)(ws + WS_BBF);
  short* btf = (short*)(ws + WS_BTF);
  const int t = threadIdx.x;
#pragma unroll
  for (int i = 0; i < 4; ++i) {
    int idx = t + 256 * i;  // 0..1023
    int r = idx >> 6, dq = idx & 63;
    float4 v = ((const float4*)books)[(size_t)(k * Ss + s0 + r) * 64 + dq];
    short4v h = {f2bf(v.x), f2bf(v.y), f2bf(v.z), f2bf(v.w)};
    *(short4v*)&bbf[(size_t)(k * Ss + s0 + r) * 256 + dq * 4] = h;
    *(short4v*)&tile[r * 256 + dq * 4] = h;
  }
  __syncthreads();
  const int d = t;  // 0..255
  short vals[16];
#pragma unroll
  for (int r = 0; r < 16; ++r) vals[r] = tile[r * 256 + d];
  bf16x8 lo, hi;
#pragma unroll
  for (int r = 0; r < 8; ++r) { lo[r] = vals[r]; hi[r] = vals[r + 8]; }
  size_t base = ((size_t)(k * 256 + d)) * 512 + s0;
  *(bf16x8*)&btf[base] = lo;
  *(bf16x8*)&btf[base + 8] = hi;
}

// ---------------- K4: wbooks bf16 (B,S,D) and wb2 (B,S) ----------------
__global__ void __launch_bounds__(256) wbooks_kernel(
    const float* __restrict__ books, float* __restrict__ ws) {
  const int bs = blockIdx.x;           // b*512 + s
  const int b = bs >> 9, s = bs & 511;
  const int d = threadIdx.x;
  const float* cp = ws + WS_CP + b * 16;
  float acc = 0.f;
#pragma unroll
  for (int k = 0; k < 16; ++k)
    acc = fmaf(cp[k], books[((size_t)(k * Ss + s)) * Dd + d], acc);
  short* wbf = (short*)(ws + WS_WBF);
  wbf[((size_t)(b * Ss + s)) * Dd + d] = f2bf(acc);
  if (d == 0) {
    float a2 = 0.f;
#pragma unroll
    for (int k = 0; k < 16; ++k) a2 = fmaf(cp[k], ws[WS_B2 + k * Ss + s], a2);
    ws[WS_WB2 + b * Ss + s] = a2;
  }
}

// ---------------- K5+K6 merged, 64-row tiles, 1024-thread blocks ----------------
// Theory: fused kernel is L2/L3 streaming-BW bound (~6 TB/s constant across all
// prior variants). 64-row tile with 16 waves halves operand traffic per output
// row while keeping per-wave register footprint (~112 unified) and occupancy
// (16 waves/CU) identical to the verified 32-row structure.
//   blockIdx < 256: zq. Wave w owns GEMM1 s in [w*32,w*32+32), GEMM2 d in
//   [w*16,w*16+16). C-layout: col=lane&15, row=(lane>>4)*4+reg.
//   blockIdx >= 256: mlogits (same 64-row shape vs wbooks bf16).
// Cross-wave softmax: redmax/redsum[64][17] (17-stride: conflict-free combine),
// hierarchical combine (lane t<64 owns row t) + barA2 barrier.
__global__ void __launch_bounds__(1024, 4) fused_kernel(
    const float* __restrict__ ze, const float* __restrict__ lpq,
    const float* __restrict__ ws, float* __restrict__ out) {
  __shared__ short ze_s[64 * 264];    // 33.8 KB
  __shared__ short enc_s[64 * 520];   // 66.6 KB (zq only)
  __shared__ float redmax[64][17];    // 4.3 KB
  __shared__ float redsum[64][17];    // 4.3 KB
  __shared__ float finalM[64];
  __shared__ float finalI[64];        // 1/T
  __shared__ float finalL[64];        // log(T) (mlogits only)
  __shared__ float cpk[16];

  const int t = threadIdx.x;
  const int w = t >> 6;               // 0..15
  const int lane = t & 63, c = lane & 15, q = lane >> 4;
  const float pq = prec_q(lpq);

  if (blockIdx.x < 256) {
    // ================= zq path =================
    const int b = blockIdx.x >> 4;
    const int n0 = (blockIdx.x & 15) << 6;
    const short* bbf = (const short*)(ws + WS_BBF);
    const short* btf = (const short*)(ws + WS_BTF);
    const float* b2p = ws + WS_B2;
    const float ca = 4.f * pq * LOG2E;   // score -> w-domain scale
    const float cbs = -2.f * pq * LOG2E; // b2 fold

    if (t < 16) cpk[t] = ws[WS_CP + b * 16 + t];
#pragma unroll
    for (int i = 0; i < 4; ++i) {
      int idx = t + 1024 * i;  // 0..4095
      int r = idx >> 6, dq = idx & 63;
      float4 v = ((const float4*)ze)[(size_t)(b * Nn + n0 + r) * 64 + dq];
      short4v h = {f2bf(v.x), f2bf(v.y), f2bf(v.z), f2bf(v.w)};
      *(short4v*)&ze_s[r * 264 + dq * 4] = h;
    }
    __syncthreads();

    f32x4 acc2[4];   // [rt], dt collapsed (wave owns 16 d-cols)
#pragma unroll
    for (int rt = 0; rt < 4; ++rt) acc2[rt] = (f32x4)(0.f);

    for (int k = 0; k < 16; ++k) {
      // ---- GEMM1: scores = ze . books[k]^T  (4 rt x 2 st)
      f32x4 acc1[4][2];
#pragma unroll
      for (int rt = 0; rt < 4; ++rt)
#pragma unroll
        for (int st = 0; st < 2; ++st) acc1[rt][st] = (f32x4)(0.f);
      for (int dstep = 0; dstep < 8; ++dstep) {
        bf16x8 a[4];
#pragma unroll
        for (int rt = 0; rt < 4; ++rt)
          a[rt] = *(const bf16x8*)&ze_s[(rt * 16 + c) * 264 + dstep * 32 + q * 8];
#pragma unroll
        for (int st = 0; st < 2; ++st) {
          bf16x8 bB = *(const bf16x8*)&bbf[((size_t)(k * Ss + w * 32 + st * 16 + c)) * 256 +
                                           dstep * 32 + q * 8];
#pragma unroll
          for (int rt = 0; rt < 4; ++rt)
            acc1[rt][st] = __builtin_amdgcn_mfma_f32_16x16x32_bf16(a[rt], bB, acc1[rt][st], 0, 0, 0);
        }
      }

      // ---- w-domain scores + gumbel in C-layout registers
      float cb[2];
#pragma unroll
      for (int st = 0; st < 2; ++st) cb[st] = cbs * b2p[k * Ss + w * 32 + st * 16 + c];
      float mx[4][4], sm[4][4];
#pragma unroll
      for (int rt = 0; rt < 4; ++rt)
#pragma unroll
        for (int reg = 0; reg < 4; ++reg) mx[rt][reg] = -3.0e38f;
#pragma unroll
      for (int rt = 0; rt < 4; ++rt)
#pragma unroll
        for (int st = 0; st < 2; ++st)
#pragma unroll
          for (int reg = 0; reg < 4; ++reg) {
            int row = n0 + rt * 16 + q * 4 + reg;
            uint32_t gi = ((uint32_t)(b * Nn + row) * (uint32_t)Kk + (uint32_t)k) * (uint32_t)Ss +
                          (uint32_t)(w * 32 + st * 16 + c);
            float gw = jax_gumbel_w2(KG2, gi);
            float v = fmaf(acc1[rt][st][reg], ca, cb[st]) + gw;
            acc1[rt][st][reg] = v;
            mx[rt][reg] = fmaxf(mx[rt][reg], v);
          }
#pragma unroll
      for (int m = 1; m < 16; m <<= 1)
#pragma unroll
        for (int rt = 0; rt < 4; ++rt)
#pragma unroll
          for (int reg = 0; reg < 4; ++reg)
            mx[rt][reg] = fmaxf(mx[rt][reg], __shfl_xor(mx[rt][reg], m));
      float smv[4][4];
#pragma unroll
      for (int rt = 0; rt < 4; ++rt)
#pragma unroll
        for (int reg = 0; reg < 4; ++reg) smv[rt][reg] = 0.f;
#pragma unroll
      for (int rt = 0; rt < 4; ++rt)
#pragma unroll
        for (int st = 0; st < 2; ++st)
#pragma unroll
          for (int reg = 0; reg < 4; ++reg) {
            float e = hw_exp2(acc1[rt][st][reg] - mx[rt][reg]);
            acc1[rt][st][reg] = e;
            smv[rt][reg] += e;
          }
#pragma unroll
      for (int m = 1; m < 16; m <<= 1)
#pragma unroll
        for (int rt = 0; rt < 4; ++rt)
#pragma unroll
          for (int reg = 0; reg < 4; ++reg) smv[rt][reg] += __shfl_xor(smv[rt][reg], m);
      if (c == 0) {
#pragma unroll
        for (int rt = 0; rt < 4; ++rt)
#pragma unroll
          for (int reg = 0; reg < 4; ++reg) {
            int rl = rt * 16 + q * 4 + reg;
            redmax[rl][w] = mx[rt][reg];
            redsum[rl][w] = smv[rt][reg];
          }
      }
      __syncthreads();  // barA: red arrays complete; orders enc writes after
                        // all GEMM2(k-1) reads.

      // ---- hierarchical combine: lane t<64 owns row t
      if (t < 64) {
        float M = redmax[t][0];
#pragma unroll
        for (int w2 = 1; w2 < 16; ++w2) M = fmaxf(M, redmax[t][w2]);
        float T = 0.f;
#pragma unroll
        for (int w2 = 0; w2 < 16; ++w2)
          T = fmaf(redsum[t][w2], hw_exp2(redmax[t][w2] - M), T);
        finalM[t] = M;
        finalI[t] = __builtin_amdgcn_rcpf(T);
      }
      __syncthreads();  // barA2

      // ---- normalized enc (bf16, A-layout source)
      const float cpv = cpk[k];
#pragma unroll
      for (int rt = 0; rt < 4; ++rt)
#pragma unroll
        for (int reg = 0; reg < 4; ++reg) {
          int rl = rt * 16 + q * 4 + reg;
          float scale = cpv * hw_exp2(mx[rt][reg] - finalM[rl]) * finalI[rl];
#pragma unroll
          for (int st = 0; st < 2; ++st)
            enc_s[rl * 520 + w * 32 + st * 16 + c] = f2bf(acc1[rt][st][reg] * scale);
        }
      __syncthreads();  // barB: enc complete for GEMM2

      // ---- GEMM2: zq += enc . bookT[k]
      for (int ss = 0; ss < 16; ++ss) {
        bf16x8 a[4];
#pragma unroll
        for (int rt = 0; rt < 4; ++rt)
          a[rt] = *(const bf16x8*)&enc_s[(rt * 16 + c) * 520 + ss * 32 + q * 8];
        bf16x8 bB = *(const bf16x8*)&btf[((size_t)(k * 256 + w * 16 + c)) * 512 +
                                         ss * 32 + q * 8];
#pragma unroll
        for (int rt = 0; rt < 4; ++rt)
          acc2[rt] = __builtin_amdgcn_mfma_f32_16x16x32_bf16(a[rt], bB, acc2[rt], 0, 0, 0);
      }
    }

    // ---- epilogue: C-layout -> global zq
#pragma unroll
    for (int rt = 0; rt < 4; ++rt)
#pragma unroll
      for (int reg = 0; reg < 4; ++reg) {
        int row = n0 + rt * 16 + q * 4 + reg;
        int d = w * 16 + c;
        out[(size_t)(b * Nn + row) * Dd + d] = acc2[rt][reg];
      }
  } else {
    // ================= mlogits path (64 rows) =================
    const int mbid = blockIdx.x - 256;
    const int b = mbid >> 4;
    const int n0 = (mbid & 15) << 6;
    const short* wbf = (const short*)(ws + WS_WBF);
    const float* wb2 = ws + WS_WB2;

#pragma unroll
    for (int i = 0; i < 4; ++i) {
      int idx = t + 1024 * i;
      int r = idx >> 6, dq = idx & 63;
      float4 v = ((const float4*)ze)[(size_t)(b * Nn + n0 + r) * 64 + dq];
      short4v h = {f2bf(v.x), f2bf(v.y), f2bf(v.z), f2bf(v.w)};
      *(short4v*)&ze_s[r * 264 + dq * 4] = h;
    }
    __syncthreads();

    f32x4 acc1[4][2];
#pragma unroll
    for (int rt = 0; rt < 4; ++rt)
#pragma unroll
      for (int st = 0; st < 2; ++st) acc1[rt][st] = (f32x4)(0.f);
    for (int dstep = 0; dstep < 8; ++dstep) {
      bf16x8 a[4];
#pragma unroll
      for (int rt = 0; rt < 4; ++rt)
        a[rt] = *(const bf16x8*)&ze_s[(rt * 16 + c) * 264 + dstep * 32 + q * 8];
#pragma unroll
      for (int st = 0; st < 2; ++st) {
        bf16x8 bB = *(const bf16x8*)&wbf[((size_t)(b * Ss + w * 32 + st * 16 + c)) * 256 +
                                         dstep * 32 + q * 8];
#pragma unroll
        for (int rt = 0; rt < 4; ++rt)
          acc1[rt][st] = __builtin_amdgcn_mfma_f32_16x16x32_bf16(a[rt], bB, acc1[rt][st], 0, 0, 0);
      }
    }

    float mx[4][4], sm[4][4];
#pragma unroll
    for (int rt = 0; rt < 4; ++rt)
#pragma unroll
      for (int reg = 0; reg < 4; ++reg) mx[rt][reg] = -3.0e38f;
#pragma unroll
    for (int st = 0; st < 2; ++st) {
      const float wb2v = wb2[b * Ss + w * 32 + st * 16 + c];
#pragma unroll
      for (int rt = 0; rt < 4; ++rt)
#pragma unroll
        for (int reg = 0; reg < 4; ++reg) {
          float v = (2.f * acc1[rt][st][reg] - wb2v) * pq;
          acc1[rt][st][reg] = v;
          mx[rt][reg] = fmaxf(mx[rt][reg], v);
        }
    }
#pragma unroll
    for (int m = 1; m < 16; m <<= 1)
#pragma unroll
      for (int rt = 0; rt < 4; ++rt)
#pragma unroll
        for (int reg = 0; reg < 4; ++reg)
          mx[rt][reg] = fmaxf(mx[rt][reg], __shfl_xor(mx[rt][reg], m));
#pragma unroll
    for (int rt = 0; rt < 4; ++rt)
#pragma unroll
      for (int reg = 0; reg < 4; ++reg) sm[rt][reg] = 0.f;
#pragma unroll
    for (int st = 0; st < 2; ++st)
#pragma unroll
      for (int rt = 0; rt < 4; ++rt)
#pragma unroll
        for (int reg = 0; reg < 4; ++reg)
          sm[rt][reg] += __expf(acc1[rt][st][reg] - mx[rt][reg]);
#pragma unroll
    for (int m = 1; m < 16; m <<= 1)
#pragma unroll
      for (int rt = 0; rt < 4; ++rt)
#pragma unroll
        for (int reg = 0; reg < 4; ++reg) sm[rt][reg] += __shfl_xor(sm[rt][reg], m);
    if (c == 0) {
#pragma unroll
      for (int rt = 0; rt < 4; ++rt)
#pragma unroll
        for (int reg = 0; reg < 4; ++reg) {
          int rl = rt * 16 + q * 4 + reg;
          redmax[rl][w] = mx[rt][reg];
          redsum[rl][w] = sm[rt][reg];
        }
    }
    __syncthreads();

    if (t < 64) {
      float M = redmax[t][0];
#pragma unroll
      for (int w2 = 1; w2 < 16; ++w2) M = fmaxf(M, redmax[t][w2]);
      float T = 0.f;
#pragma unroll
      for (int w2 = 0; w2 < 16; ++w2)
        T = fmaf(redsum[t][w2], __expf(redmax[t][w2] - M), T);
      finalM[t] = M;
      finalI[t] = __builtin_amdgcn_rcpf(T);
      finalL[t] = __logf(T);
    }
    __syncthreads();

#pragma unroll
    for (int rt = 0; rt < 4; ++rt)
#pragma unroll
      for (int reg = 0; reg < 4; ++reg) {
        int rl = rt * 16 + q * 4 + reg;
        const float M = finalM[rl];
        const float invT = finalI[rl];
        const float lT = finalL[rl];
        const size_t base = (size_t)(b * Nn + n0 + rl) * Ss;
#pragma unroll
        for (int st = 0; st < 2; ++st) {
          int s = w * 32 + st * 16 + c;
          float v = acc1[rt][st][reg] - M;
          out[PROB_OFF + base + s] = __expf(v) * invT;
          out[LP_OFF + base + s] = v - lT;
        }
      }
  }
}

}  // namespace

extern "C" void kernel_launch(void* const* d_in, const int* in_sizes, int n_in,
                              void* d_out, int out_size, void* d_ws, size_t ws_size,
                              hipStream_t stream) {
  (void)in_sizes; (void)n_in; (void)out_size; (void)ws_size;
  const float* ze = (const float*)d_in[0];
  const float* c_logits = (const float*)d_in[1];
  const float* books = (const float*)d_in[2];
  const float* lpq = (const float*)d_in[3];
  const float* lpq_cls = (const float*)d_in[4];
  float* out = (float*)d_out;
  float* ws = (float*)d_ws;

  hipLaunchKernelGGL(cprobs_kernel, dim3(1), dim3(256), 0, stream,
                     c_logits, lpq, lpq_cls, ws, out);
  hipLaunchKernelGGL(norms_kernel, dim3(Kk * Ss / 4), dim3(256), 0, stream, books, ws);
  hipLaunchKernelGGL(prep_kernel, dim3(Kk * 32), dim3(256), 0, stream, books, ws);
  hipLaunchKernelGGL(wbooks_kernel, dim3(Bsz * Ss), dim3(256), 0, stream, books, ws);
  hipLaunchKernelGGL(fused_kernel, dim3(512), dim3(1024), 0, stream,
                     ze, lpq, ws, out);
}